// Round 2
// baseline (11524.554 us; speedup 1.0000x reference)
//
#include <hip/hip_runtime.h>
#include <math.h>

#define BB 32
#define TT 128
#define EE 512
#define UU 1024
#define GG 4096   // 4*UU, row stride of weight matrices
#define HP 36     // padded LDS row stride in floats (16B-aligned rows)

typedef float f32x4 __attribute__((ext_vector_type(4)));

__device__ __forceinline__ float sigmoidf_(float x){ return 1.0f/(1.0f + expf(-x)); }

// ---------------- embedding gather into xT[t][e][b] ----------------
__global__ void gather_k(const int* __restrict__ tokens, const float* __restrict__ emb,
                         float* __restrict__ xT){
  int idx = blockIdx.x*256 + threadIdx.x;           // total T*E*B = 2^21
  int b = idx & 31, e = (idx>>5)&511, t = idx>>14;
  int tok = tokens[b*TT + t];
  xT[idx] = emb[(size_t)tok*EE + e];
}

// ---------------- per-step kernel 1: z0 = x@W0 + h@U0 + b0 -> h0 ; zp = h@U1 ----
// Grid 256 blocks x 512 threads. Block bid owns u in [bid*4, bid*4+4)
// (16 gate-cols per matrix). Thread microtile 4b x 4c, 16-way k-split.
__global__ __launch_bounds__(512) void lstm_k2(
    const float* __restrict__ xTt,   // [512][32]  (t-slice of xT)
    const float* __restrict__ W0,    // [512][4096]   original layout
    const float* __restrict__ U0,    // [1024][4096]
    const float* __restrict__ U1,    // [1024][4096]
    const float* __restrict__ b0,
    const float* __restrict__ hT,    // [1024][32]
    const float* __restrict__ cT,    // [1024][32]
    float* __restrict__ h0T,         // [1024][32]
    float* __restrict__ zp)          // [256][512]
{
  __shared__ float hs[256*HP];       // 36.9 KB staging chunk
  __shared__ float red[8][512];      // 16 KB k-split reduction
  __shared__ float zbuf[32*17];      // padded z for gate reads
  int tid = threadIdx.x;
  int bid = blockIdx.x;
  int ub = bid*4;
  int cq = tid & 3, bq = (tid>>2)&7, kq = tid>>5;   // kq in [0,16)
  int col = cq*UU + ub;
  float acc [4][4] = {{0}};          // z0 partials (x@W0 + h@U0)
  float acc2[4][4] = {{0}};          // h@U1 partials

  // ---- P1a: x @ W0 (K = 512, 2 chunks of 256) ----
  for (int ch = 0; ch < EE; ch += 256) {
    __syncthreads();
    const f32x4* s4 = (const f32x4*)(xTt + ch*BB);
    for (int i = tid; i < 2048; i += 512) {
      int r = i>>3, c4 = i&7;
      *(f32x4*)&hs[r*HP + c4*4] = s4[i];
    }
    __syncthreads();
    int kb = kq*16;
    #pragma unroll 2
    for (int kk=0; kk<16; kk+=4){
      int k = kb + kk;
      int kg = ch + k;
      f32x4 w[4], hv[4];
      #pragma unroll
      for (int j=0;j<4;++j) w[j] = *(const f32x4*)(W0 + (size_t)(kg+j)*GG + col);
      #pragma unroll
      for (int j=0;j<4;++j) hv[j] = *(const f32x4*)&hs[(k+j)*HP + bq*4];
      #pragma unroll
      for (int j=0;j<4;++j)
        #pragma unroll
        for (int bi=0;bi<4;++bi)
          #pragma unroll
          for (int ci=0;ci<4;++ci)
            acc[bi][ci] += hv[j][bi]*w[j][ci];
    }
  }

  // ---- P1b + P2: h @ U0 and h @ U1 (K = 1024, 4 chunks), shared h staging ----
  for (int ch = 0; ch < UU; ch += 256) {
    __syncthreads();
    const f32x4* s4 = (const f32x4*)(hT + ch*BB);
    for (int i = tid; i < 2048; i += 512) {
      int r = i>>3, c4 = i&7;
      *(f32x4*)&hs[r*HP + c4*4] = s4[i];
    }
    __syncthreads();
    int kb = kq*16;
    #pragma unroll 2
    for (int kk=0; kk<16; kk+=4){
      int k = kb + kk;
      int kg = ch + k;
      f32x4 w[4], w2[4], hv[4];
      #pragma unroll
      for (int j=0;j<4;++j) w[j]  = *(const f32x4*)(U0 + (size_t)(kg+j)*GG + col);
      #pragma unroll
      for (int j=0;j<4;++j) w2[j] = *(const f32x4*)(U1 + (size_t)(kg+j)*GG + col);
      #pragma unroll
      for (int j=0;j<4;++j) hv[j] = *(const f32x4*)&hs[(k+j)*HP + bq*4];
      #pragma unroll
      for (int j=0;j<4;++j)
        #pragma unroll
        for (int bi=0;bi<4;++bi)
          #pragma unroll
          for (int ci=0;ci<4;++ci){
            acc [bi][ci] += hv[j][bi]*w [j][ci];
            acc2[bi][ci] += hv[j][bi]*w2[j][ci];
          }
    }
  }

  // ---- pre-reduce k-slice pairs within the wave (tid bit5 <-> kq bit0) ----
  #pragma unroll
  for (int bi=0;bi<4;++bi)
    #pragma unroll
    for (int ci=0;ci<4;++ci){
      acc [bi][ci] += __shfl_xor(acc [bi][ci], 32, 64);
      acc2[bi][ci] += __shfl_xor(acc2[bi][ci], 32, 64);
    }

  // ---- reduce z0 over kq ----
  if ((tid & 32) == 0){
    #pragma unroll
    for (int bi=0;bi<4;++bi){
      int out = (bq*4+bi)*16 + cq*4;
      f32x4 v = {acc[bi][0],acc[bi][1],acc[bi][2],acc[bi][3]};
      *(f32x4*)&red[kq>>1][out] = v;
    }
  }
  __syncthreads();
  {
    int o = tid;
    if (o < 512){
      float s = 0.f;
      #pragma unroll
      for (int q=0;q<8;++q) s += red[q][o];
      zbuf[(o>>4)*17 + (o&15)] = s;
    }
  }
  __syncthreads();
  // ---- write h@U1 partials to red ----
  if ((tid & 32) == 0){
    #pragma unroll
    for (int bi=0;bi<4;++bi){
      int out = (bq*4+bi)*16 + cq*4;
      f32x4 v = {acc2[bi][0],acc2[bi][1],acc2[bi][2],acc2[bi][3]};
      *(f32x4*)&red[kq>>1][out] = v;
    }
  }
  __syncthreads();
  // ---- cell-0 gates: (b, uj) ----
  if (tid < 128){
    int b = tid>>2, uj = tid&3;
    int u = ub + uj;
    float zi = zbuf[b*17 + 0 + uj] + b0[0*UU + u];
    float zf = zbuf[b*17 + 4 + uj] + b0[1*UU + u];
    float zg = zbuf[b*17 + 8 + uj] + b0[2*UU + u];
    float zo = zbuf[b*17 +12 + uj] + b0[3*UU + u];
    float c0 = sigmoidf_(zf)*cT[u*BB + b] + sigmoidf_(zi)*tanhf(zg);
    h0T[u*BB + b] = sigmoidf_(zo)*tanhf(c0);   // cell-0 c is discarded (reference quirk)
  }
  // ---- reduce h@U1 over kq -> zp (global) ----
  {
    int o = tid;
    if (o < 512){
      float s = 0.f;
      #pragma unroll
      for (int q=0;q<8;++q) s += red[q][o];
      zp[bid*512 + o] = s;
    }
  }
}

// ---------------- per-step kernel 2: z1 = h0@W1 + zp + b1 -> h,c ----------------
__global__ __launch_bounds__(512) void lstm_k3(
    const float* __restrict__ h0T,   // [1024][32]
    const float* __restrict__ W1,    // [1024][4096]  original layout
    const float* __restrict__ b1,
    const float* __restrict__ zp,    // [256][512]
    float* __restrict__ hT,          // [1024][32]
    float* __restrict__ cT)          // [1024][32]
{
  __shared__ float hs[256*HP];
  __shared__ float red[8][512];
  __shared__ float zbuf[32*17];
  int tid = threadIdx.x, bid = blockIdx.x, ub = bid*4;
  int cq = tid&3, bq = (tid>>2)&7, kq = tid>>5;
  int col = cq*UU + ub;
  float acc[4][4] = {{0}};

  for (int ch=0; ch<UU; ch+=256){
    __syncthreads();
    const f32x4* s4 = (const f32x4*)(h0T + ch*BB);
    for (int i=tid;i<2048;i+=512){ int r=i>>3,c4=i&7; *(f32x4*)&hs[r*HP+c4*4]=s4[i]; }
    __syncthreads();
    int kb = kq*16;
    #pragma unroll 2
    for (int kk=0;kk<16;kk+=4){
      int k = kb+kk, kg = ch+k;
      f32x4 w[4], hv[4];
      #pragma unroll
      for (int j=0;j<4;++j) w[j] = *(const f32x4*)(W1 + (size_t)(kg+j)*GG + col);
      #pragma unroll
      for (int j=0;j<4;++j) hv[j] = *(const f32x4*)&hs[(k+j)*HP + bq*4];
      #pragma unroll
      for (int j=0;j<4;++j)
        #pragma unroll
        for (int bi=0;bi<4;++bi)
          #pragma unroll
          for (int ci=0;ci<4;++ci)
            acc[bi][ci] += hv[j][bi]*w[j][ci];
    }
  }

  #pragma unroll
  for (int bi=0;bi<4;++bi)
    #pragma unroll
    for (int ci=0;ci<4;++ci)
      acc[bi][ci] += __shfl_xor(acc[bi][ci], 32, 64);

  if ((tid & 32) == 0){
    #pragma unroll
    for (int bi=0;bi<4;++bi){
      int out = (bq*4+bi)*16 + cq*4;
      f32x4 v = {acc[bi][0],acc[bi][1],acc[bi][2],acc[bi][3]};
      *(f32x4*)&red[kq>>1][out] = v;
    }
  }
  __syncthreads();
  {
    int o = tid;
    if (o < 512){
      float s = 0.f;
      #pragma unroll
      for (int q=0;q<8;++q) s += red[q][o];
      zbuf[(o>>4)*17 + (o&15)] = s;
    }
  }
  __syncthreads();
  if (tid < 128){
    int b = tid>>2, uj = tid&3;
    int u = ub + uj;
    const float* zpb = zp + bid*512 + b*16;
    float zi = zbuf[b*17 + 0 + uj] + zpb[ 0+uj] + b1[0*UU + u];
    float zf = zbuf[b*17 + 4 + uj] + zpb[ 4+uj] + b1[1*UU + u];
    float zg = zbuf[b*17 + 8 + uj] + zpb[ 8+uj] + b1[2*UU + u];
    float zo = zbuf[b*17 +12 + uj] + zpb[12+uj] + b1[3*UU + u];
    float cold = cT[u*BB + b];
    float cn = sigmoidf_(zf)*cold + sigmoidf_(zi)*tanhf(zg);
    float hn = sigmoidf_(zo)*tanhf(cn);
    hT[u*BB + b] = hn;
    cT[u*BB + b] = cn;
  }
}

// ---------------- final: out[b] = sigmoid(h_last . fc_w + fc_b) ----------------
__global__ __launch_bounds__(256) void lstm_out(const float* __restrict__ hT,
    const float* __restrict__ fcw, const float* __restrict__ fcb, float* __restrict__ out){
  __shared__ float r[256];
  int b = blockIdx.x, tid = threadIdx.x;
  float s = 0.f;
  for (int u = tid; u < UU; u += 256) s += hT[u*BB + b] * fcw[u];
  r[tid] = s; __syncthreads();
  for (int st=128; st>0; st>>=1){ if (tid<st) r[tid]+=r[tid+st]; __syncthreads(); }
  if (tid==0) out[b] = 1.0f/(1.0f+expf(-(r[0]+fcb[0])));
}

extern "C" void kernel_launch(void* const* d_in, const int* in_sizes, int n_in,
                              void* d_out, int out_size, void* d_ws, size_t ws_size,
                              hipStream_t stream) {
  const int*   tokens = (const int*)  d_in[0];
  const float* emb    = (const float*)d_in[1];
  const float* W0     = (const float*)d_in[2];
  const float* U0     = (const float*)d_in[3];
  const float* b0     = (const float*)d_in[4];
  const float* W1     = (const float*)d_in[5];   // dict order: W1 before U1
  const float* U1     = (const float*)d_in[6];
  const float* b1     = (const float*)d_in[7];
  const float* fcw    = (const float*)d_in[8];
  const float* fcb    = (const float*)d_in[9];

  float* ws  = (float*)d_ws;
  float* xT  = ws;                         // 128*512*32 = 2,097,152 floats (8 MB)
  float* hT  = xT  + (size_t)TT*EE*BB;     // 1024*32
  float* cT  = hT  + 32768;
  float* h0T = cT  + 32768;
  float* zp  = h0T + 32768;                // 256*512

  // zero initial h, c (ws is re-poisoned to 0xAA before every timed launch)
  hipMemsetAsync(hT, 0, (size_t)2*32768*sizeof(float), stream);

  gather_k<<<8192, 256, 0, stream>>>(tokens, emb, xT);

  for (int t = 0; t < TT; ++t) {
    lstm_k2<<<256, 512, 0, stream>>>(xT + (size_t)t*EE*BB, W0, U0, U1, b0, hT, cT, h0T, zp);
    lstm_k3<<<256, 512, 0, stream>>>(h0T, W1, b1, zp, hT, cT);
  }
  lstm_out<<<32, 256, 0, stream>>>(hT, fcw, fcb, (float*)d_out);
}